// Round 2
// baseline (746.316 us; speedup 1.0000x reference)
//
#include <hip/hip_runtime.h>
#include <math.h>

// TopK router: logits = x @ W^T + bias; top-2; softmax over the 2; scatter.
// x: [N=16384, H=4096] fp32, W: [E=64, H=4096] fp32, bias: [64] fp32.
// d_out: [N*64] final (fp32) then [N*2] selected_experts written as floats.
//
// Scheme: one ROW per LANE (wave = 64 rows), acc[64] experts per lane.
// W addresses are wave-uniform (readfirstlane'd k-base) -> s_load_dwordx4
// on the scalar pipe; X is one per-lane global_load_dwordx4 per 4 k.
// K split 4-way across the block's 4 waves; ordered LDS reduce at the end.

constexpr int E_EXPERTS = 64;
constexpr int H_DIM = 4096;
constexpr int BLOCK = 256;   // 4 waves
constexpr int ROWS = 64;     // one row per lane
constexpr int KQ = H_DIM / 4;  // 1024 k per wave
constexpr int PAD = 66;      // LDS row pad (floats): 2-way banks, b64-aligned

__global__ __launch_bounds__(BLOCK, 1) void topk_router_kernel(
    const float* __restrict__ x, const float* __restrict__ w,
    const float* __restrict__ bias, float* __restrict__ out_final,
    float* __restrict__ out_idx) {
  __shared__ float part[ROWS][PAD];

  const int tid = threadIdx.x;
  const int lane = tid & 63;
  const int wave = tid >> 6;
  const int rowBase = blockIdx.x * ROWS;

  // Wave-uniform k-base, forced into SGPR so W loads become s_load.
  const int kq = __builtin_amdgcn_readfirstlane(wave * KQ);
  const float* __restrict__ xr = x + (size_t)(rowBase + lane) * H_DIM + kq;
  const float* __restrict__ wbase = w + kq;

  float acc[E_EXPERTS];
#pragma unroll
  for (int e = 0; e < E_EXPERTS; ++e) acc[e] = 0.f;

  float4 xv[4], xn[4];
#pragma unroll
  for (int i = 0; i < 4; ++i)
    xv[i] = *reinterpret_cast<const float4*>(xr + i * 4);

  constexpr int NO = KQ / 16;  // 64 outer iters, 16 k each (one 64B line/lane)
  for (int o = 0; o < NO; ++o) {
    // Prefetch next 16 k's worth of x (double-buffered).
    if (o + 1 < NO) {
      const float* __restrict__ xo = xr + (size_t)(o + 1) * 16;
#pragma unroll
      for (int i = 0; i < 4; ++i)
        xn[i] = *reinterpret_cast<const float4*>(xo + i * 4);
    }
    const float* __restrict__ wo = wbase + o * 16;
#pragma unroll
    for (int e = 0; e < E_EXPERTS; ++e) {
      const float* __restrict__ wr = wo + (size_t)e * H_DIM;
#pragma unroll
      for (int i = 0; i < 4; ++i) {
        float4 wv = *reinterpret_cast<const float4*>(wr + i * 4);
        acc[e] += (xv[i].x * wv.x + xv[i].y * wv.y) +
                  (xv[i].z * wv.z + xv[i].w * wv.w);
      }
    }
#pragma unroll
    for (int i = 0; i < 4; ++i) xv[i] = xn[i];
  }

  // Ordered cross-wave accumulate into LDS (deterministic).
  for (int ws = 0; ws < 4; ++ws) {
    if (wave == ws) {
      if (ws == 0) {
#pragma unroll
        for (int e = 0; e < E_EXPERTS; e += 2)
          *reinterpret_cast<float2*>(&part[lane][e]) =
              make_float2(acc[e], acc[e + 1]);
      } else {
#pragma unroll
        for (int e = 0; e < E_EXPERTS; e += 2) {
          float2 p = *reinterpret_cast<const float2*>(&part[lane][e]);
          p.x += acc[e];
          p.y += acc[e + 1];
          *reinterpret_cast<float2*>(&part[lane][e]) = p;
        }
      }
    }
    __syncthreads();
  }

  // Epilogue: 4 threads per row, 16 experts each; top-2 with stable ties.
  const int r = tid >> 2;
  const int eb = (tid & 3) * 16;
  const int n = rowBase + r;

  float av = -INFINITY, bv = -INFINITY;
  int ai = E_EXPERTS, bi = E_EXPERTS;
#pragma unroll
  for (int j = 0; j < 16; ++j) {
    int e = eb + j;
    float v = part[r][e] + bias[e];
    bool beats_a = (v > av) || (v == av && e < ai);
    bool beats_b = (v > bv) || (v == bv && e < bi);
    if (beats_a) {
      bv = av; bi = ai; av = v; ai = e;
    } else if (beats_b) {
      bv = v; bi = e;
    }
  }
  // Merge across the 4 threads sharing this row (shfl_xor d=1,2).
#pragma unroll
  for (int d = 1; d < 4; d <<= 1) {
    float av2 = __shfl_xor(av, d);
    float bv2 = __shfl_xor(bv, d);
    int ai2 = __shfl_xor(ai, d);
    int bi2 = __shfl_xor(bi, d);
    bool afirst = (av > av2) || (av == av2 && ai < ai2);
    float na, nb;
    int nai, nbi;
    if (afirst) {
      na = av; nai = ai;
      bool t = (bv > av2) || (bv == av2 && bi < ai2);
      nb = t ? bv : av2;
      nbi = t ? bi : ai2;
    } else {
      na = av2; nai = ai2;
      bool t = (av > bv2) || (av == bv2 && ai < bi2);
      nb = t ? av : bv2;
      nbi = t ? ai : bi2;
    }
    av = na; ai = nai; bv = nb; bi = nbi;
  }

  // softmax over the two (descending) logits.
  float e1 = expf(bv - av);
  float denom = 1.0f + e1;
  float p0 = 1.0f / denom;
  float p1 = e1 / denom;

#pragma unroll
  for (int i = 0; i < 4; ++i) {
    float4 o4;
    float* po = &o4.x;
#pragma unroll
    for (int j = 0; j < 4; ++j) {
      int e = eb + i * 4 + j;
      po[j] = (e == ai) ? p0 : (e == bi) ? p1 : 0.0f;
    }
    *reinterpret_cast<float4*>(&out_final[(size_t)n * E_EXPERTS + eb + i * 4]) =
        o4;
  }
  if ((tid & 3) == 0) {
    out_idx[(size_t)n * 2 + 0] = (float)ai;
    out_idx[(size_t)n * 2 + 1] = (float)bi;
  }
}

extern "C" void kernel_launch(void* const* d_in, const int* in_sizes, int n_in,
                              void* d_out, int out_size, void* d_ws,
                              size_t ws_size, hipStream_t stream) {
  const float* x = (const float*)d_in[0];
  const float* w = (const float*)d_in[1];
  const float* bias = (const float*)d_in[2];
  const int N = in_sizes[0] / H_DIM;  // 16384
  float* out_final = (float*)d_out;
  float* out_idx = out_final + (size_t)N * E_EXPERTS;

  dim3 grid(N / ROWS);
  dim3 block(BLOCK);
  topk_router_kernel<<<grid, block, 0, stream>>>(x, w, bias, out_final,
                                                 out_idx);
}

// Round 3
// 574.989 us; speedup vs baseline: 1.2980x; 1.2980x over previous
//
#include <hip/hip_runtime.h>
#include <math.h>

// TopK router: logits = x @ W^T + bias; top-2; softmax over the 2; scatter.
// x: [N=16384, H=4096] fp32, W: [E=64, H=4096] fp32, bias: [64] fp32.
// d_out: [N*64] final (fp32) then [N*2] selected_experts written as floats.
//
// One ROW per LANE; acc[64 experts] in VGPRs (float4 acc[16], static idx).
// W addresses are wave-uniform -> scalar loads (SGPR operand FMAs), batched
// 4 experts x 8 k = 32 SGPRs per batch so the unrolled body never exceeds
// the SGPR budget (round-2 spill fix). K split 8 ways across 8 waves
// (2 waves/SIMD to cover s_load latency); deterministic tree reduce in LDS.

constexpr int E_EXPERTS = 64;
constexpr int H_DIM = 4096;
constexpr int BLOCK = 512;          // 8 waves
constexpr int ROWS = 64;            // one row per lane
constexpr int KSPLIT = 8;
constexpr int KQ = H_DIM / KSPLIT;  // 512 k per wave
constexpr int KC = 8;               // k per outer iteration
constexpr int NO = KQ / KC;         // 64
constexpr int PADE = 68;            // floats per row: 272B, 16B-aligned

__device__ __forceinline__ float4 ld4(const float* p) {
  return *reinterpret_cast<const float4*>(p);
}

__global__ __launch_bounds__(BLOCK, 2) void topk_router_kernel(
    const float* __restrict__ x, const float* __restrict__ w,
    const float* __restrict__ bias, float* __restrict__ out_final,
    float* __restrict__ out_idx) {
  __shared__ float part[4][ROWS][PADE];

  const int tid = threadIdx.x;
  const int lane = tid & 63;
  const int wave = tid >> 6;
  const int rowBase = blockIdx.x * ROWS;

  // Wave-uniform k-base in SGPR so W loads stay scalar.
  const int kq = __builtin_amdgcn_readfirstlane(wave * KQ);
  const float* __restrict__ xr = x + (size_t)(rowBase + lane) * H_DIM + kq;
  const float* __restrict__ wq = w + kq;

  float4 acc[16];  // acc[eg] covers experts eg*4 .. eg*4+3
#pragma unroll
  for (int i = 0; i < 16; ++i) acc[i] = make_float4(0.f, 0.f, 0.f, 0.f);

  float4 xa = ld4(xr), xb = ld4(xr + 4);
  for (int o = 0; o < NO; ++o) {
    float4 xan, xbn;
    if (o + 1 < NO) {  // prefetch next 8 k (hides VMEM latency under FMAs)
      xan = ld4(xr + (o + 1) * KC);
      xbn = ld4(xr + (o + 1) * KC + 4);
    } else {
      xan = xa; xbn = xb;
    }
#pragma unroll
    for (int eg = 0; eg < 16; ++eg) {
      const float* wr = wq + (size_t)(eg * 4) * H_DIM + o * KC;
      float4 w0a = ld4(wr), w0b = ld4(wr + 4);
      float4 w1a = ld4(wr + H_DIM), w1b = ld4(wr + H_DIM + 4);
      float4 w2a = ld4(wr + 2 * H_DIM), w2b = ld4(wr + 2 * H_DIM + 4);
      float4 w3a = ld4(wr + 3 * H_DIM), w3b = ld4(wr + 3 * H_DIM + 4);
      acc[eg].x += xa.x * w0a.x + xa.y * w0a.y + xa.z * w0a.z + xa.w * w0a.w +
                   xb.x * w0b.x + xb.y * w0b.y + xb.z * w0b.z + xb.w * w0b.w;
      acc[eg].y += xa.x * w1a.x + xa.y * w1a.y + xa.z * w1a.z + xa.w * w1a.w +
                   xb.x * w1b.x + xb.y * w1b.y + xb.z * w1b.z + xb.w * w1b.w;
      acc[eg].z += xa.x * w2a.x + xa.y * w2a.y + xa.z * w2a.z + xa.w * w2a.w +
                   xb.x * w2b.x + xb.y * w2b.y + xb.z * w2b.z + xb.w * w2b.w;
      acc[eg].w += xa.x * w3a.x + xa.y * w3a.y + xa.z * w3a.z + xa.w * w3a.w +
                   xb.x * w3b.x + xb.y * w3b.y + xb.z * w3b.z + xb.w * w3b.w;
    }
    xa = xan;
    xb = xbn;
  }

  // Deterministic pairwise-tree reduction of the 8 k-partials in LDS.
  if (wave < 4) {
#pragma unroll
    for (int i = 0; i < 16; ++i)
      *reinterpret_cast<float4*>(&part[wave][lane][i * 4]) = acc[i];
  }
  __syncthreads();
  if (wave >= 4) {
    const int d = wave - 4;
#pragma unroll
    for (int i = 0; i < 16; ++i) {
      float4 p = *reinterpret_cast<const float4*>(&part[d][lane][i * 4]);
      p.x += acc[i].x; p.y += acc[i].y; p.z += acc[i].z; p.w += acc[i].w;
      *reinterpret_cast<float4*>(&part[d][lane][i * 4]) = p;
    }
  }
  __syncthreads();
  if (wave < 2) {
#pragma unroll
    for (int i = 0; i < 16; ++i) {
      float4 p = *reinterpret_cast<const float4*>(&part[wave][lane][i * 4]);
      float4 q = *reinterpret_cast<const float4*>(&part[wave + 2][lane][i * 4]);
      p.x += q.x; p.y += q.y; p.z += q.z; p.w += q.w;
      *reinterpret_cast<float4*>(&part[wave][lane][i * 4]) = p;
    }
  }
  __syncthreads();
  if (wave == 0) {
#pragma unroll
    for (int i = 0; i < 16; ++i) {
      float4 p = *reinterpret_cast<const float4*>(&part[0][lane][i * 4]);
      float4 q = *reinterpret_cast<const float4*>(&part[1][lane][i * 4]);
      p.x += q.x; p.y += q.y; p.z += q.z; p.w += q.w;
      *reinterpret_cast<float4*>(&part[0][lane][i * 4]) = p;
    }
  }
  __syncthreads();

  // Epilogue: 8 threads per row, 8 experts each; stable top-2 + softmax.
  const int r = tid >> 3;
  const int eb = (tid & 7) * 8;
  const int n = rowBase + r;

  float v8[8];
#pragma unroll
  for (int i = 0; i < 2; ++i) {
    float4 p = *reinterpret_cast<const float4*>(&part[0][r][eb + i * 4]);
    float4 b4 = ld4(bias + eb + i * 4);
    v8[i * 4 + 0] = p.x + b4.x;
    v8[i * 4 + 1] = p.y + b4.y;
    v8[i * 4 + 2] = p.z + b4.z;
    v8[i * 4 + 3] = p.w + b4.w;
  }

  float av = -INFINITY, bv = -INFINITY;
  int ai = E_EXPERTS, bi = E_EXPERTS;
#pragma unroll
  for (int j = 0; j < 8; ++j) {
    int e = eb + j;
    float v = v8[j];
    bool beats_a = (v > av) || (v == av && e < ai);
    bool beats_b = (v > bv) || (v == bv && e < bi);
    if (beats_a) {
      bv = av; bi = ai; av = v; ai = e;
    } else if (beats_b) {
      bv = v; bi = e;
    }
  }
#pragma unroll
  for (int d = 1; d < 8; d <<= 1) {
    float av2 = __shfl_xor(av, d);
    float bv2 = __shfl_xor(bv, d);
    int ai2 = __shfl_xor(ai, d);
    int bi2 = __shfl_xor(bi, d);
    bool afirst = (av > av2) || (av == av2 && ai < ai2);
    float na, nb;
    int nai, nbi;
    if (afirst) {
      na = av; nai = ai;
      bool t = (bv > av2) || (bv == av2 && bi < ai2);
      nb = t ? bv : av2;
      nbi = t ? bi : ai2;
    } else {
      na = av2; nai = ai2;
      bool t = (av > bv2) || (av == bv2 && ai < bi2);
      nb = t ? av : bv2;
      nbi = t ? ai : bi2;
    }
    av = na; ai = nai; bv = nb; bi = nbi;
  }

  float e1 = expf(bv - av);
  float denom = 1.0f + e1;
  float p0 = 1.0f / denom;
  float p1 = e1 / denom;

#pragma unroll
  for (int i = 0; i < 2; ++i) {
    float4 o4;
    float* po = &o4.x;
#pragma unroll
    for (int j = 0; j < 4; ++j) {
      int e = eb + i * 4 + j;
      po[j] = (e == ai) ? p0 : (e == bi) ? p1 : 0.0f;
    }
    *reinterpret_cast<float4*>(
        &out_final[(size_t)n * E_EXPERTS + eb + i * 4]) = o4;
  }
  if ((tid & 7) == 0) {
    out_idx[(size_t)n * 2 + 0] = (float)ai;
    out_idx[(size_t)n * 2 + 1] = (float)bi;
  }
}

extern "C" void kernel_launch(void* const* d_in, const int* in_sizes, int n_in,
                              void* d_out, int out_size, void* d_ws,
                              size_t ws_size, hipStream_t stream) {
  const float* x = (const float*)d_in[0];
  const float* w = (const float*)d_in[1];
  const float* bias = (const float*)d_in[2];
  const int N = in_sizes[0] / H_DIM;  // 16384
  float* out_final = (float*)d_out;
  float* out_idx = out_final + (size_t)N * E_EXPERTS;

  dim3 grid(N / ROWS);
  dim3 block(BLOCK);
  topk_router_kernel<<<grid, block, 0, stream>>>(x, w, bias, out_final,
                                                 out_idx);
}

// Round 5
// 96.511 us; speedup vs baseline: 7.7329x; 5.9577x over previous
//
#include <hip/hip_runtime.h>
#include <math.h>

// TopK router: logits = x @ W^T + bias; top-2; softmax over the 2; scatter.
// x: [N=16384, H=4096] fp32, W: [E=64, H=4096] fp32, bias: [64] fp32.
// d_out: [N*64] final (fp32) then [N*2] selected_experts written as floats.
//
// MFMA path, round-5 fix: 3-term bf16 split (h=trunc, m=trunc, l=RNE;
// residuals exact by Sterbenz) -> per-element reconstruct error ~2^-25.
// 6 products per tile: hh + hm + mh + mm + hl + lh (dropped terms <=2^-24).
// Round 4's 2-term split (~2^-18 -> logit err ~3e-4) flipped near-tie rows
// vs the fp64 np reference; fp32 rounds (err ~1e-5) always passed, so the
// tie margin sits between -> 3-term lands at ~1e-6, safely below.
// No LDS staging: A-frags (row=lane&15, k=(lane>>4)*8+j) and B-frags
// (col=lane&15 = expert, W already [e][k] = B^T) load straight from global.

constexpr int E_EXPERTS = 64;
constexpr int H_DIM = 4096;
constexpr int BLOCK = 256;           // 4 waves
constexpr int ROWS_B = 32;           // rows per block
constexpr int KSPLIT = 4;            // one K-quarter per wave
constexpr int KQ = H_DIM / KSPLIT;   // 1024
constexpr int KC = 32;               // k per chunk = one MFMA k-step
constexpr int NCH = KQ / KC;         // 32

typedef __attribute__((ext_vector_type(8))) short short8;
typedef __attribute__((ext_vector_type(4))) float f32x4;

__device__ __forceinline__ float4 ld4(const float* p) {
  return *reinterpret_cast<const float4*>(p);
}

__device__ __forceinline__ unsigned short bf_rne(float x) {
  unsigned u = __builtin_bit_cast(unsigned, x);
  return (unsigned short)((u + 0x7fffu + ((u >> 16) & 1u)) >> 16);
}
__device__ __forceinline__ float bf2f(unsigned short b) {
  return __builtin_bit_cast(float, ((unsigned)b) << 16);
}
// x = h + m + l + err, |err| <= 2^-25 |x|.
__device__ __forceinline__ void split3(float x, short& h, short& m, short& l) {
  unsigned short hb =
      (unsigned short)(__builtin_bit_cast(unsigned, x) >> 16);  // trunc
  float r1 = x - bf2f(hb);  // exact (Sterbenz)
  unsigned short mb =
      (unsigned short)(__builtin_bit_cast(unsigned, r1) >> 16);  // trunc
  float r2 = r1 - bf2f(mb);  // exact
  h = (short)hb;
  m = (short)mb;
  l = (short)bf_rne(r2);
}
__device__ __forceinline__ void split3_8(float4 a, float4 b, short8& h,
                                         short8& m, short8& l) {
  short hh, mm, ll;
  split3(a.x, hh, mm, ll); h[0] = hh; m[0] = mm; l[0] = ll;
  split3(a.y, hh, mm, ll); h[1] = hh; m[1] = mm; l[1] = ll;
  split3(a.z, hh, mm, ll); h[2] = hh; m[2] = mm; l[2] = ll;
  split3(a.w, hh, mm, ll); h[3] = hh; m[3] = mm; l[3] = ll;
  split3(b.x, hh, mm, ll); h[4] = hh; m[4] = mm; l[4] = ll;
  split3(b.y, hh, mm, ll); h[5] = hh; m[5] = mm; l[5] = ll;
  split3(b.z, hh, mm, ll); h[6] = hh; m[6] = mm; l[6] = ll;
  split3(b.w, hh, mm, ll); h[7] = hh; m[7] = mm; l[7] = ll;
}

__global__ __launch_bounds__(BLOCK, 2) void topk_router_mfma(
    const float* __restrict__ x, const float* __restrict__ w,
    const float* __restrict__ bias, float* __restrict__ out_final,
    float* __restrict__ out_idx) {
  __shared__ float part[KSPLIT][ROWS_B][E_EXPERTS + 4];

  const int tid = threadIdx.x;
  const int lane = tid & 63;
  const int kg = tid >> 6;  // K-quarter of this wave
  const int rowBase = blockIdx.x * ROWS_B;
  const int lrow = lane & 15;
  const int lk = (lane >> 4) * 8;

  const float* __restrict__ xp0 =
      x + (size_t)(rowBase + lrow) * H_DIM + kg * KQ + lk;
  const float* __restrict__ xp1 = xp0 + (size_t)16 * H_DIM;
  const float* __restrict__ wp = w + (size_t)lrow * H_DIM + kg * KQ + lk;

  f32x4 acc00 = {0.f, 0.f, 0.f, 0.f}, acc01 = acc00, acc02 = acc00,
        acc03 = acc00, acc10 = acc00, acc11 = acc00, acc12 = acc00,
        acc13 = acc00;

  float4 xf0a, xf0b, xf1a, xf1b;
  float4 wf0a, wf0b, wf1a, wf1b, wf2a, wf2b, wf3a, wf3b;

#define LOADC(c)                                                            \
  do {                                                                      \
    const size_t o = (size_t)(c)*KC;                                        \
    xf0a = ld4(xp0 + o); xf0b = ld4(xp0 + o + 4);                           \
    xf1a = ld4(xp1 + o); xf1b = ld4(xp1 + o + 4);                           \
    wf0a = ld4(wp + o); wf0b = ld4(wp + o + 4);                             \
    wf1a = ld4(wp + o + (size_t)16 * H_DIM);                                \
    wf1b = ld4(wp + o + (size_t)16 * H_DIM + 4);                            \
    wf2a = ld4(wp + o + (size_t)32 * H_DIM);                                \
    wf2b = ld4(wp + o + (size_t)32 * H_DIM + 4);                            \
    wf3a = ld4(wp + o + (size_t)48 * H_DIM);                                \
    wf3b = ld4(wp + o + (size_t)48 * H_DIM + 4);                            \
  } while (0)

  LOADC(0);
  for (int c = 0; c < NCH; ++c) {
    short8 ah0, am0, al0, ah1, am1, al1;
    short8 b0h, b0m, b0l, b1h, b1m, b1l, b2h, b2m, b2l, b3h, b3m, b3l;
    split3_8(xf0a, xf0b, ah0, am0, al0);
    split3_8(xf1a, xf1b, ah1, am1, al1);
    split3_8(wf0a, wf0b, b0h, b0m, b0l);
    split3_8(wf1a, wf1b, b1h, b1m, b1l);
    split3_8(wf2a, wf2b, b2h, b2m, b2l);
    split3_8(wf3a, wf3b, b3h, b3m, b3l);
    if (c + 1 < NCH) LOADC(c + 1);  // issue next chunk; MFMA hides latency

#define MM(d, a, b) d = __builtin_amdgcn_mfma_f32_16x16x32_bf16(a, b, d, 0, 0, 0)
#define PROD6(d, Ah, Am, Al, Bh, Bm, Bl)                      \
  MM(d, Ah, Bh); MM(d, Ah, Bm); MM(d, Am, Bh); MM(d, Am, Bm); \
  MM(d, Ah, Bl); MM(d, Al, Bh)
    PROD6(acc00, ah0, am0, al0, b0h, b0m, b0l);
    PROD6(acc10, ah1, am1, al1, b0h, b0m, b0l);
    PROD6(acc01, ah0, am0, al0, b1h, b1m, b1l);
    PROD6(acc11, ah1, am1, al1, b1h, b1m, b1l);
    PROD6(acc02, ah0, am0, al0, b2h, b2m, b2l);
    PROD6(acc12, ah1, am1, al1, b2h, b2m, b2l);
    PROD6(acc03, ah0, am0, al0, b3h, b3m, b3l);
    PROD6(acc13, ah1, am1, al1, b3h, b3m, b3l);
  }

  // C/D layout (m89-verified): col = lane&15 (expert), row = (lane>>4)*4+reg.
  const int pr = (lane >> 4) * 4;
  const int pc = lane & 15;
#define STORE_ACC(A, rf, bf)                              \
  part[kg][(rf)*16 + pr + 0][(bf)*16 + pc] = A[0];        \
  part[kg][(rf)*16 + pr + 1][(bf)*16 + pc] = A[1];        \
  part[kg][(rf)*16 + pr + 2][(bf)*16 + pc] = A[2];        \
  part[kg][(rf)*16 + pr + 3][(bf)*16 + pc] = A[3];
  STORE_ACC(acc00, 0, 0)
  STORE_ACC(acc01, 0, 1)
  STORE_ACC(acc02, 0, 2)
  STORE_ACC(acc03, 0, 3)
  STORE_ACC(acc10, 1, 0)
  STORE_ACC(acc11, 1, 1)
  STORE_ACC(acc12, 1, 2)
  STORE_ACC(acc13, 1, 3)
  __syncthreads();

  // Epilogue: 8 threads/row, 8 experts each; ordered 4-way partial sum,
  // stable top-2 scan, shfl_xor merge (d=1,2,4), softmax, scatter.
  const int r = tid >> 3;
  const int eb = (tid & 7) * 8;
  const int n = rowBase + r;

  float v8[8];
#pragma unroll
  for (int j = 0; j < 8; ++j) {
    int e = eb + j;
    v8[j] = ((part[0][r][e] + part[1][r][e]) +
             (part[2][r][e] + part[3][r][e])) +
            bias[e];
  }

  float av = -INFINITY, bv = -INFINITY;
  int ai = E_EXPERTS, bi = E_EXPERTS;
#pragma unroll
  for (int j = 0; j < 8; ++j) {
    int e = eb + j;
    float v = v8[j];
    bool beats_a = (v > av) || (v == av && e < ai);
    bool beats_b = (v > bv) || (v == bv && e < bi);
    if (beats_a) {
      bv = av; bi = ai; av = v; ai = e;
    } else if (beats_b) {
      bv = v; bi = e;
    }
  }
#pragma unroll
  for (int d = 1; d < 8; d <<= 1) {
    float av2 = __shfl_xor(av, d);
    float bv2 = __shfl_xor(bv, d);
    int ai2 = __shfl_xor(ai, d);
    int bi2 = __shfl_xor(bi, d);
    bool afirst = (av > av2) || (av == av2 && ai < ai2);
    float na, nb;
    int nai, nbi;
    if (afirst) {
      na = av; nai = ai;
      bool t = (bv > av2) || (bv == av2 && bi < ai2);
      nb = t ? bv : av2;
      nbi = t ? bi : ai2;
    } else {
      na = av2; nai = ai2;
      bool t = (av > bv2) || (av == bv2 && ai < bi2);
      nb = t ? av : bv2;
      nbi = t ? ai : bi2;
    }
    av = na; ai = nai; bv = nb; bi = nbi;
  }

  float e1 = expf(bv - av);
  float denom = 1.0f + e1;
  float p0 = 1.0f / denom;
  float p1 = e1 / denom;

#pragma unroll
  for (int i = 0; i < 2; ++i) {
    float4 o4;
    float* po = &o4.x;
#pragma unroll
    for (int j = 0; j < 4; ++j) {
      int e = eb + i * 4 + j;
      po[j] = (e == ai) ? p0 : (e == bi) ? p1 : 0.0f;
    }
    *reinterpret_cast<float4*>(
        &out_final[(size_t)n * E_EXPERTS + eb + i * 4]) = o4;
  }
  if ((tid & 7) == 0) {
    out_idx[(size_t)n * 2 + 0] = (float)ai;
    out_idx[(size_t)n * 2 + 1] = (float)bi;
  }
}

extern "C" void kernel_launch(void* const* d_in, const int* in_sizes, int n_in,
                              void* d_out, int out_size, void* d_ws,
                              size_t ws_size, hipStream_t stream) {
  const float* x = (const float*)d_in[0];
  const float* w = (const float*)d_in[1];
  const float* bias = (const float*)d_in[2];
  const int N = in_sizes[0] / H_DIM;  // 16384
  float* out_final = (float*)d_out;
  float* out_idx = out_final + (size_t)N * E_EXPERTS;

  dim3 grid(N / ROWS_B);
  dim3 block(BLOCK);
  topk_router_mfma<<<grid, block, 0, stream>>>(x, w, bias, out_final, out_idx);
}